// Round 2
// baseline (5542.419 us; speedup 1.0000x reference)
//
#include <hip/hip_runtime.h>
#include <cstdint>
#include <cstddef>

// DiscontinuedGRU: SEQ=2048, B=64, I=256, H=256.
// Pipeline:
//   K0a: X fp32 -> bf16 (ws)
//   K0b: Wih_f|Wih_b fp32 -> bf16 concat (ws)
//   K1 : GX[131072][1536] f16 = Xb @ Wcat^T + (bih + bhh_{r,z} folded; bhh_n NOT folded)
//   K2 : 128 WGs (one per (dir,batch) chain), Whh f16 register-resident,
//        v_dot2 matvec per step + gate math; h state in LDS (f16).
//        R2 (single coupled change vs R0): GX/D software-pipelined one step ahead
//        with UNCONDITIONAL clamped loads (counted vmcnt possible), and in-loop
//        barriers wait lgkmcnt(0) only so prefetch/stores stay in flight across them.
//        (R1's DPP reduce + conditional D-load reverted: bank-conflict counter proved
//        ds_swizzle was never the conflict source, and absolute VALU time rose.)
// ws layout: Xb 67,108,864 B | Wcat 786,432 B | GX 402,653,184 B  (total ~449 MB)

#define SEQ 2048
#define BATCH 64

typedef __attribute__((ext_vector_type(8))) short short8;
typedef __attribute__((ext_vector_type(4))) float floatx4;
typedef __attribute__((ext_vector_type(2))) _Float16 h2;

#if defined(__has_builtin)
#if __has_builtin(__builtin_amdgcn_fdot2)
#define HAS_FDOT2 1
#endif
#endif

__device__ inline float fdot2f(h2 a, h2 b, float c){
#ifdef HAS_FDOT2
  return __builtin_amdgcn_fdot2(a, b, c, false);
#else
  return c + (float)a.x * (float)b.x + (float)a.y * (float)b.y;
#endif
}

// Workgroup barrier that drains LDS only (lgkmcnt). Global loads (GX/D prefetch) and
// global stores (out) stay in flight across it — they need no intra-kernel ordering:
// GX/D are read-only, each out location is written exactly once and never read.
// The waitcnt is assembler-encoded (no manual imm); s_barrier via builtin so the
// scheduler still sees a real barrier.
__device__ inline void barrier_lds(){
  asm volatile("s_waitcnt lgkmcnt(0)" ::: "memory");
  __builtin_amdgcn_s_barrier();
}

__device__ inline unsigned short f2bf(float f){
  union { float f; unsigned int u; } a; a.f = f;
  unsigned int u = a.u;
  unsigned int r = (u + 0x7fffu + ((u >> 16) & 1u)) >> 16;
  return (unsigned short)r;
}

__global__ __launch_bounds__(256) void cvt_x_kernel(const float* __restrict__ X,
                                                    unsigned short* __restrict__ Xb){
  size_t i = (size_t)blockIdx.x * 256 + threadIdx.x;   // one float4 per thread
  float4 v = ((const float4*)X)[i];
  ushort4 o;
  o.x = f2bf(v.x); o.y = f2bf(v.y); o.z = f2bf(v.z); o.w = f2bf(v.w);
  ((ushort4*)Xb)[i] = o;
}

__global__ __launch_bounds__(256) void cvt_w_kernel(const float* __restrict__ Wf,
                                                    const float* __restrict__ Wb,
                                                    unsigned short* __restrict__ Wcat){
  int i = blockIdx.x * 256 + threadIdx.x;              // 0..393215
  float v = (i < 768 * 256) ? Wf[i] : Wb[i - 768 * 256];
  Wcat[i] = f2bf(v);
}

// ---------------- GX GEMM: M=131072, N=1536, K=256, bf16 MFMA ----------------
// Block: 256 thr (4 waves). Tile BM=64, BN=128, BK=64. Wave w: rows [16w,16w+16) x 128 cols.
__global__ __launch_bounds__(256) void gx_gemm_kernel(
    const unsigned short* __restrict__ Xb,    // [131072][256] bf16
    const unsigned short* __restrict__ Wcat,  // [1536][256]  bf16 (row n, k-contig = B^T)
    const float* __restrict__ bih_f, const float* __restrict__ bhh_f,
    const float* __restrict__ bih_b, const float* __restrict__ bhh_b,
    _Float16* __restrict__ GX)                // [131072][1536] f16
{
  __shared__ unsigned short Al[64][72];   // +8 pad: stride 36 words
  __shared__ unsigned short Bl[128][72];
  const int tid  = threadIdx.x;
  const int lane = tid & 63;
  const int w    = tid >> 6;
  const size_t m0 = (size_t)blockIdx.x * 64;
  const int    n0 = blockIdx.y * 128;

  floatx4 acc[8];
  #pragma unroll
  for (int i = 0; i < 8; i++) acc[i] = (floatx4)0.f;

  const int ar = tid >> 2, ak = (tid & 3) * 16;   // A stage: 16 halves/thread
  const int bn = tid >> 1, bk = (tid & 1) * 32;   // B stage: 32 halves/thread

  for (int kc = 0; kc < 4; kc++){
    const int kb = kc * 64;
    { const uint4* s = (const uint4*)(Xb + (m0 + ar) * 256 + kb + ak);
      uint4 u0 = s[0], u1 = s[1];
      *(uint4*)&Al[ar][ak]     = u0;
      *(uint4*)&Al[ar][ak + 8] = u1;
    }
    { const uint4* s = (const uint4*)(Wcat + (size_t)(n0 + bn) * 256 + kb + bk);
      uint4 u0 = s[0], u1 = s[1], u2 = s[2], u3 = s[3];
      *(uint4*)&Bl[bn][bk]      = u0;
      *(uint4*)&Bl[bn][bk + 8]  = u1;
      *(uint4*)&Bl[bn][bk + 16] = u2;
      *(uint4*)&Bl[bn][bk + 24] = u3;
    }
    __syncthreads();
    #pragma unroll
    for (int ks = 0; ks < 2; ks++){
      const int kl = ks * 32 + (lane >> 4) * 8;
      short8 af = *(const short8*)&Al[w * 16 + (lane & 15)][kl];
      #pragma unroll
      for (int nt = 0; nt < 8; nt++){
        short8 bf = *(const short8*)&Bl[nt * 16 + (lane & 15)][kl];
        acc[nt] = __builtin_amdgcn_mfma_f32_16x16x32_bf16(af, bf, acc[nt], 0, 0, 0);
      }
    }
    __syncthreads();
  }
  // epilogue: D col = lane&15, row = (lane>>4)*4 + reg  [verified m89/m91]
  #pragma unroll
  for (int nt = 0; nt < 8; nt++){
    const int n_g = n0 + nt * 16 + (lane & 15);
    const int nl  = (n_g < 768) ? n_g : n_g - 768;
    const float* bih = (n_g < 768) ? bih_f : bih_b;
    const float* bhh = (n_g < 768) ? bhh_f : bhh_b;
    // fold bih (all gates) + bhh for r,z only; bhh_n applied inside scan (r * (hn + bhh_n))
    const float bias = bih[nl] + ((nl < 512) ? bhh[nl] : 0.f);
    #pragma unroll
    for (int r = 0; r < 4; r++){
      const size_t m_g = m0 + w * 16 + (lane >> 4) * 4 + r;
      GX[m_g * 1536 + n_g] = (_Float16)(acc[nt][r] + bias);
    }
  }
}

// ---------------- Recurrent scan: 128 WGs x 1024 thr, 1 chain each ----------------
// thread t: j0 = t>>3 (0..127), kq = t&7 (k-slice of 32). Owns 6 gh rows: j0 + 128q.
// Whh f16 in 96 VGPRs/thread. h state: LDS f16, slice-padded (stride 40 halves) so the
// 8 distinct per-wave b128 addresses land on 8 distinct bank quads (conflict-free).
__global__ __launch_bounds__(1024) void gru_scan_kernel(
    const float* __restrict__ Whh_f, const float* __restrict__ Whh_b,
    const float* __restrict__ bhh_f, const float* __restrict__ bhh_b,
    const int* __restrict__ D,
    const _Float16* __restrict__ GX,
    float* __restrict__ out)
{
  const int wg  = blockIdx.x;       // 0..127
  const int dir = wg & 1;
  const int b   = wg >> 1;
  const float* Whh = dir ? Whh_b : Whh_f;
  const float* bhh = dir ? bhh_b : bhh_f;
  const int tid   = threadIdx.x;
  const int j0    = tid >> 3;
  const int kq    = tid & 7;
  const int kbase = kq * 32;

  __shared__ _Float16 hbuf[8 * 40];   // slice q at q*40 (32 valid + 8 pad)
  __shared__ float    gh2[2 * 768];   // two partial copies (kq groups 0-3 / 4-7)

  // persistent weights: rows j0 + 128q, k in [kbase, kbase+32)
  h2 wreg[6][4][4];
  #pragma unroll
  for (int q = 0; q < 6; q++){
    const float* wr = Whh + (size_t)(j0 + 128 * q) * 256 + kbase;
    #pragma unroll
    for (int c = 0; c < 4; c++){
      float4 f0 = *(const float4*)(wr + c * 8);
      float4 f1 = *(const float4*)(wr + c * 8 + 4);
      wreg[q][c][0] = h2{(_Float16)f0.x, (_Float16)f0.y};
      wreg[q][c][1] = h2{(_Float16)f0.z, (_Float16)f0.w};
      wreg[q][c][2] = h2{(_Float16)f1.x, (_Float16)f1.y};
      wreg[q][c][3] = h2{(_Float16)f1.z, (_Float16)f1.w};
    }
  }

  const bool gate = (tid < 256);      // waves 0-3, whole waves -> no divergence cost elsewhere
  float h_reg = 0.f;                  // fp32 h_in[j] for gate thread j = tid
  float bhhn  = 0.f;
  _Float16 pgr = (_Float16)0.f, pgz = (_Float16)0.f, pgn = (_Float16)0.f; // GX pipeline regs
  float mreg = 0.f;                                                       // D pipeline reg
  if (gate){
    bhhn = bhh[512 + tid];
    hbuf[((tid >> 5) * 40) + (tid & 31)] = (_Float16)0.f;
    // prime the pipeline for step 0
    const int t0 = dir ? (SEQ - 1) : 0;
    const _Float16* gx0 = GX + ((size_t)t0 * BATCH + b) * 1536 + dir * 768;
    pgr = gx0[tid]; pgz = gx0[256 + tid]; pgn = gx0[512 + tid];
    // mask consumed after step 0's hnew: fwd -> D[t0+1], bwd -> D[t0]
    const int tm0 = dir ? t0 : 1;
    mreg = (float)D[(size_t)tm0 * BATCH + b];
  }
  __syncthreads();

  for (int step = 0; step < SEQ; step++){
    const int t = dir ? (SEQ - 1 - step) : step;

    float acc[6] = {0.f, 0.f, 0.f, 0.f, 0.f, 0.f};
    #pragma unroll
    for (int c = 0; c < 4; c++){
      uint4 u = *(const uint4*)&hbuf[kq * 40 + c * 8];
      h2 p0 = __builtin_bit_cast(h2, u.x);
      h2 p1 = __builtin_bit_cast(h2, u.y);
      h2 p2 = __builtin_bit_cast(h2, u.z);
      h2 p3 = __builtin_bit_cast(h2, u.w);
      #pragma unroll
      for (int q = 0; q < 6; q++){
        acc[q] = fdot2f(wreg[q][c][0], p0, acc[q]);
        acc[q] = fdot2f(wreg[q][c][1], p1, acc[q]);
        acc[q] = fdot2f(wreg[q][c][2], p2, acc[q]);
        acc[q] = fdot2f(wreg[q][c][3], p3, acc[q]);
      }
    }
    // reduce kq pairs/quads (stays in wave: lanes differ in bits 0,1)
    #pragma unroll
    for (int q = 0; q < 6; q++){
      acc[q] += __shfl_xor(acc[q], 1);
      acc[q] += __shfl_xor(acc[q], 2);
    }
    if ((tid & 3) == 0){               // kq in {0,4}
      float* g = gh2 + ((tid >> 2) & 1) * 768;
      #pragma unroll
      for (int q = 0; q < 6; q++) g[j0 + 128 * q] = acc[q];
    }
    barrier_lds();

    if (gate){
      const int j = tid;
      // consume values prefetched one step ago (loads have had the whole matvec to land)
      const float gxr = (float)pgr;
      const float gxz = (float)pgz;
      const float gxn = (float)pgn;
      const float mcur = mreg;
      // issue next step's loads NOW — unconditional, clamped indices (tail values are
      // dead: the final step's h_reg update is never read). Straight-line body so the
      // waitcnt pass can count outstanding ops instead of draining vmcnt(0).
      {
        const int tn = dir ? ((t > 0) ? t - 1 : 0) : ((t < SEQ - 1) ? t + 1 : SEQ - 1);
        const _Float16* gxp = GX + ((size_t)tn * BATCH + b) * 1536 + dir * 768;
        pgr = gxp[j]; pgz = gxp[256 + j]; pgn = gxp[512 + j];
        const int tm = dir ? tn : ((tn < SEQ - 1) ? tn + 1 : SEQ - 1);
        mreg = (float)D[(size_t)tm * BATCH + b];
      }
      const float ghr = gh2[j]       + gh2[768 + j];
      const float ghz = gh2[256 + j] + gh2[768 + 256 + j];
      const float ghn = gh2[512 + j] + gh2[768 + 512 + j];
      const float r = 1.f / (1.f + __expf(-(gxr + ghr)));
      const float z = 1.f / (1.f + __expf(-(gxz + ghz)));
      const float e = __expf(2.f * (gxn + r * (ghn + bhhn)));
      const float n = 1.f - 2.f / (e + 1.f);
      const float hnew = (1.f - z) * n + z * h_reg;
      const size_t row = (size_t)t * BATCH + b;
      out[row * 512 + dir * 256 + j] = hnew;
      h_reg = (1.f - mcur) * hnew;
      hbuf[((j >> 5) * 40) + (j & 31)] = (_Float16)h_reg;
    }
    barrier_lds();
  }
}

extern "C" void kernel_launch(void* const* d_in, const int* in_sizes, int n_in,
                              void* d_out, int out_size, void* d_ws, size_t ws_size,
                              hipStream_t stream)
{
  const float* X     = (const float*)d_in[0];
  const int*   D     = (const int*)  d_in[1];
  const float* Wih_f = (const float*)d_in[2];
  const float* Whh_f = (const float*)d_in[3];
  const float* bih_f = (const float*)d_in[4];
  const float* bhh_f = (const float*)d_in[5];
  const float* Wih_b = (const float*)d_in[6];
  const float* Whh_b = (const float*)d_in[7];
  const float* bih_b = (const float*)d_in[8];
  const float* bhh_b = (const float*)d_in[9];
  float* out = (float*)d_out;

  char* ws = (char*)d_ws;
  unsigned short* Xb   = (unsigned short*)ws;               // 67,108,864 B
  unsigned short* Wcat = (unsigned short*)(ws + 67108864);  //    786,432 B
  _Float16*       GX   = (_Float16*)(ws + 67895296);        // 402,653,184 B

  cvt_x_kernel<<<dim3(32768), 256, 0, stream>>>(X, Xb);
  cvt_w_kernel<<<dim3(1536), 256, 0, stream>>>(Wih_f, Wih_b, Wcat);
  gx_gemm_kernel<<<dim3(2048, 12), 256, 0, stream>>>(Xb, Wcat, bih_f, bhh_f, bih_b, bhh_b, GX);
  gru_scan_kernel<<<dim3(128), 1024, 0, stream>>>(Whh_f, Whh_b, bhh_f, bhh_b, D, GX, out);
}

// Round 3
// 3945.206 us; speedup vs baseline: 1.4048x; 1.4048x over previous
//
#include <hip/hip_runtime.h>
#include <cstdint>
#include <cstddef>

// DiscontinuedGRU: SEQ=2048, B=64, I=256, H=256.
// Pipeline:
//   K0a: X fp32 -> bf16 (ws)
//   K0b: Wih_f|Wih_b fp32 -> bf16 concat (ws)
//   K1 : GX[131072][1536] f16 = Xb @ Wcat^T + (bih + bhh_{r,z} folded; bhh_n NOT folded)
//   K2 : 128 WGs (one per (dir,batch) chain), Whh f16 register-resident,
//        v_dot2 matvec per step + gate math; h state in LDS (f16).
//   R3 = R0 + ONE change: kq-quad reduce via DPP quad_perm (VALU pipe) instead of
//        __shfl_xor (ds_swizzle, DS pipe). DS pipe is the bottleneck (~2600cy/step of
//        4170: 64 b128 hbuf reads + 192 swizzles + 96 gh2 writes); swizzles are the
//        largest removable item (~1100cy).
//   PERMANENT REVERTS (measured poison): lgkm-only asm barrier (+~2700cy/step, R1/R2);
//        GX/D prefetch-one-step-ahead restructure (neutral-to-negative, R2).
// ws layout: Xb 67,108,864 B | Wcat 786,432 B | GX 402,653,184 B  (total ~449 MB)

#define SEQ 2048
#define BATCH 64

typedef __attribute__((ext_vector_type(8))) short short8;
typedef __attribute__((ext_vector_type(4))) float floatx4;
typedef __attribute__((ext_vector_type(2))) _Float16 h2;

#if defined(__has_builtin)
#if __has_builtin(__builtin_amdgcn_fdot2)
#define HAS_FDOT2 1
#endif
#if __has_builtin(__builtin_amdgcn_update_dpp)
#define HAS_DPP 1
#endif
#endif

__device__ inline float fdot2f(h2 a, h2 b, float c){
#ifdef HAS_FDOT2
  return __builtin_amdgcn_fdot2(a, b, c, false);
#else
  return c + (float)a.x * (float)b.x + (float)a.y * (float)b.y;
#endif
}

// sum over the 4 lanes of each quad (lane bits 0,1) — VALU DPP, no DS-pipe traffic.
// All lanes are active at the call site (convergent matvec phase), so old=0 /
// bound_ctrl=false is safe. Verified correct in R1.
__device__ inline float quad_add(float x){
#ifdef HAS_DPP
  int t1 = __builtin_amdgcn_update_dpp(0, __builtin_bit_cast(int, x), 0xB1, 0xF, 0xF, false); // quad_perm [1,0,3,2]
  x += __builtin_bit_cast(float, t1);
  int t2 = __builtin_amdgcn_update_dpp(0, __builtin_bit_cast(int, x), 0x4E, 0xF, 0xF, false); // quad_perm [2,3,0,1]
  x += __builtin_bit_cast(float, t2);
  return x;
#else
  x += __shfl_xor(x, 1);
  x += __shfl_xor(x, 2);
  return x;
#endif
}

__device__ inline unsigned short f2bf(float f){
  union { float f; unsigned int u; } a; a.f = f;
  unsigned int u = a.u;
  unsigned int r = (u + 0x7fffu + ((u >> 16) & 1u)) >> 16;
  return (unsigned short)r;
}

__global__ __launch_bounds__(256) void cvt_x_kernel(const float* __restrict__ X,
                                                    unsigned short* __restrict__ Xb){
  size_t i = (size_t)blockIdx.x * 256 + threadIdx.x;   // one float4 per thread
  float4 v = ((const float4*)X)[i];
  ushort4 o;
  o.x = f2bf(v.x); o.y = f2bf(v.y); o.z = f2bf(v.z); o.w = f2bf(v.w);
  ((ushort4*)Xb)[i] = o;
}

__global__ __launch_bounds__(256) void cvt_w_kernel(const float* __restrict__ Wf,
                                                    const float* __restrict__ Wb,
                                                    unsigned short* __restrict__ Wcat){
  int i = blockIdx.x * 256 + threadIdx.x;              // 0..393215
  float v = (i < 768 * 256) ? Wf[i] : Wb[i - 768 * 256];
  Wcat[i] = f2bf(v);
}

// ---------------- GX GEMM: M=131072, N=1536, K=256, bf16 MFMA ----------------
// Block: 256 thr (4 waves). Tile BM=64, BN=128, BK=64. Wave w: rows [16w,16w+16) x 128 cols.
__global__ __launch_bounds__(256) void gx_gemm_kernel(
    const unsigned short* __restrict__ Xb,    // [131072][256] bf16
    const unsigned short* __restrict__ Wcat,  // [1536][256]  bf16 (row n, k-contig = B^T)
    const float* __restrict__ bih_f, const float* __restrict__ bhh_f,
    const float* __restrict__ bih_b, const float* __restrict__ bhh_b,
    _Float16* __restrict__ GX)                // [131072][1536] f16
{
  __shared__ unsigned short Al[64][72];   // +8 pad: stride 36 words
  __shared__ unsigned short Bl[128][72];
  const int tid  = threadIdx.x;
  const int lane = tid & 63;
  const int w    = tid >> 6;
  const size_t m0 = (size_t)blockIdx.x * 64;
  const int    n0 = blockIdx.y * 128;

  floatx4 acc[8];
  #pragma unroll
  for (int i = 0; i < 8; i++) acc[i] = (floatx4)0.f;

  const int ar = tid >> 2, ak = (tid & 3) * 16;   // A stage: 16 halves/thread
  const int bn = tid >> 1, bk = (tid & 1) * 32;   // B stage: 32 halves/thread

  for (int kc = 0; kc < 4; kc++){
    const int kb = kc * 64;
    { const uint4* s = (const uint4*)(Xb + (m0 + ar) * 256 + kb + ak);
      uint4 u0 = s[0], u1 = s[1];
      *(uint4*)&Al[ar][ak]     = u0;
      *(uint4*)&Al[ar][ak + 8] = u1;
    }
    { const uint4* s = (const uint4*)(Wcat + (size_t)(n0 + bn) * 256 + kb + bk);
      uint4 u0 = s[0], u1 = s[1], u2 = s[2], u3 = s[3];
      *(uint4*)&Bl[bn][bk]      = u0;
      *(uint4*)&Bl[bn][bk + 8]  = u1;
      *(uint4*)&Bl[bn][bk + 16] = u2;
      *(uint4*)&Bl[bn][bk + 24] = u3;
    }
    __syncthreads();
    #pragma unroll
    for (int ks = 0; ks < 2; ks++){
      const int kl = ks * 32 + (lane >> 4) * 8;
      short8 af = *(const short8*)&Al[w * 16 + (lane & 15)][kl];
      #pragma unroll
      for (int nt = 0; nt < 8; nt++){
        short8 bf = *(const short8*)&Bl[nt * 16 + (lane & 15)][kl];
        acc[nt] = __builtin_amdgcn_mfma_f32_16x16x32_bf16(af, bf, acc[nt], 0, 0, 0);
      }
    }
    __syncthreads();
  }
  // epilogue: D col = lane&15, row = (lane>>4)*4 + reg  [verified m89/m91]
  #pragma unroll
  for (int nt = 0; nt < 8; nt++){
    const int n_g = n0 + nt * 16 + (lane & 15);
    const int nl  = (n_g < 768) ? n_g : n_g - 768;
    const float* bih = (n_g < 768) ? bih_f : bih_b;
    const float* bhh = (n_g < 768) ? bhh_f : bhh_b;
    // fold bih (all gates) + bhh for r,z only; bhh_n applied inside scan (r * (hn + bhh_n))
    const float bias = bih[nl] + ((nl < 512) ? bhh[nl] : 0.f);
    #pragma unroll
    for (int r = 0; r < 4; r++){
      const size_t m_g = m0 + w * 16 + (lane >> 4) * 4 + r;
      GX[m_g * 1536 + n_g] = (_Float16)(acc[nt][r] + bias);
    }
  }
}

// ---------------- Recurrent scan: 128 WGs x 1024 thr, 1 chain each ----------------
// thread t: j0 = t>>3 (0..127), kq = t&7 (k-slice of 32). Owns 6 gh rows: j0 + 128q.
// Whh f16 in 96 VGPRs/thread. h state: LDS f16, slice-padded (stride 40 halves) so the
// 8 distinct per-wave b128 addresses land on 8 distinct bank quads (conflict-free).
__global__ __launch_bounds__(1024) void gru_scan_kernel(
    const float* __restrict__ Whh_f, const float* __restrict__ Whh_b,
    const float* __restrict__ bhh_f, const float* __restrict__ bhh_b,
    const int* __restrict__ D,
    const _Float16* __restrict__ GX,
    float* __restrict__ out)
{
  const int wg  = blockIdx.x;       // 0..127
  const int dir = wg & 1;
  const int b   = wg >> 1;
  const float* Whh = dir ? Whh_b : Whh_f;
  const float* bhh = dir ? bhh_b : bhh_f;
  const int tid   = threadIdx.x;
  const int j0    = tid >> 3;
  const int kq    = tid & 7;
  const int kbase = kq * 32;

  __shared__ _Float16 hbuf[8 * 40];   // slice q at q*40 (32 valid + 8 pad)
  __shared__ float    gh2[2 * 768];   // two partial copies (kq groups 0-3 / 4-7)

  // persistent weights: rows j0 + 128q, k in [kbase, kbase+32)
  h2 wreg[6][4][4];
  #pragma unroll
  for (int q = 0; q < 6; q++){
    const float* wr = Whh + (size_t)(j0 + 128 * q) * 256 + kbase;
    #pragma unroll
    for (int c = 0; c < 4; c++){
      float4 f0 = *(const float4*)(wr + c * 8);
      float4 f1 = *(const float4*)(wr + c * 8 + 4);
      wreg[q][c][0] = h2{(_Float16)f0.x, (_Float16)f0.y};
      wreg[q][c][1] = h2{(_Float16)f0.z, (_Float16)f0.w};
      wreg[q][c][2] = h2{(_Float16)f1.x, (_Float16)f1.y};
      wreg[q][c][3] = h2{(_Float16)f1.z, (_Float16)f1.w};
    }
  }

  const bool gate = (tid < 256);      // waves 0-3, whole waves -> no divergence cost elsewhere
  float h_reg = 0.f;                  // fp32 h_in[j] for gate thread j = tid
  float bhhn  = 0.f;
  if (gate){
    bhhn = bhh[512 + tid];
    hbuf[((tid >> 5) * 40) + (tid & 31)] = (_Float16)0.f;
  }
  __syncthreads();

  for (int step = 0; step < SEQ; step++){
    const int t = dir ? (SEQ - 1 - step) : step;

    float acc[6] = {0.f, 0.f, 0.f, 0.f, 0.f, 0.f};
    #pragma unroll
    for (int c = 0; c < 4; c++){
      uint4 u = *(const uint4*)&hbuf[kq * 40 + c * 8];
      h2 p0 = __builtin_bit_cast(h2, u.x);
      h2 p1 = __builtin_bit_cast(h2, u.y);
      h2 p2 = __builtin_bit_cast(h2, u.z);
      h2 p3 = __builtin_bit_cast(h2, u.w);
      #pragma unroll
      for (int q = 0; q < 6; q++){
        acc[q] = fdot2f(wreg[q][c][0], p0, acc[q]);
        acc[q] = fdot2f(wreg[q][c][1], p1, acc[q]);
        acc[q] = fdot2f(wreg[q][c][2], p2, acc[q]);
        acc[q] = fdot2f(wreg[q][c][3], p3, acc[q]);
      }
    }
    // reduce kq pairs/quads on the VALU pipe (DPP quad_perm) — keeps the DS pipe,
    // which is the bottleneck resource, free of 192 swizzle instrs/step.
    #pragma unroll
    for (int q = 0; q < 6; q++) acc[q] = quad_add(acc[q]);
    if ((tid & 3) == 0){               // kq in {0,4}
      float* g = gh2 + ((tid >> 2) & 1) * 768;
      #pragma unroll
      for (int q = 0; q < 6; q++) g[j0 + 128 * q] = acc[q];
    }
    __syncthreads();

    if (gate){
      const int j = tid;
      const size_t row = (size_t)t * BATCH + b;
      const _Float16* gx = GX + row * 1536 + dir * 768;
      const float gxr = (float)gx[j];
      const float gxz = (float)gx[256 + j];
      const float gxn = (float)gx[512 + j];
      const float ghr = gh2[j]       + gh2[768 + j];
      const float ghz = gh2[256 + j] + gh2[768 + 256 + j];
      const float ghn = gh2[512 + j] + gh2[768 + 512 + j];
      const float r = 1.f / (1.f + __expf(-(gxr + ghr)));
      const float z = 1.f / (1.f + __expf(-(gxz + ghz)));
      const float e = __expf(2.f * (gxn + r * (ghn + bhhn)));
      const float n = 1.f - 2.f / (e + 1.f);
      const float hnew = (1.f - z) * n + z * h_reg;
      out[row * 512 + dir * 256 + j] = hnew;
      // mask for the NEXT processed step: fwd uses D[t+1]; bwd (next is t-1) uses D[t]
      float mnext;
      if (dir == 0) mnext = (step < SEQ - 1) ? (float)D[(size_t)(t + 1) * BATCH + b] : 0.f;
      else          mnext = (float)D[(size_t)t * BATCH + b];
      h_reg = (1.f - mnext) * hnew;
      hbuf[((j >> 5) * 40) + (j & 31)] = (_Float16)h_reg;
    }
    __syncthreads();
  }
}

extern "C" void kernel_launch(void* const* d_in, const int* in_sizes, int n_in,
                              void* d_out, int out_size, void* d_ws, size_t ws_size,
                              hipStream_t stream)
{
  const float* X     = (const float*)d_in[0];
  const int*   D     = (const int*)  d_in[1];
  const float* Wih_f = (const float*)d_in[2];
  const float* Whh_f = (const float*)d_in[3];
  const float* bih_f = (const float*)d_in[4];
  const float* bhh_f = (const float*)d_in[5];
  const float* Wih_b = (const float*)d_in[6];
  const float* Whh_b = (const float*)d_in[7];
  const float* bih_b = (const float*)d_in[8];
  const float* bhh_b = (const float*)d_in[9];
  float* out = (float*)d_out;

  char* ws = (char*)d_ws;
  unsigned short* Xb   = (unsigned short*)ws;               // 67,108,864 B
  unsigned short* Wcat = (unsigned short*)(ws + 67108864);  //    786,432 B
  _Float16*       GX   = (_Float16*)(ws + 67895296);        // 402,653,184 B

  cvt_x_kernel<<<dim3(32768), 256, 0, stream>>>(X, Xb);
  cvt_w_kernel<<<dim3(1536), 256, 0, stream>>>(Wih_f, Wih_b, Wcat);
  gx_gemm_kernel<<<dim3(2048, 12), 256, 0, stream>>>(Xb, Wcat, bih_f, bhh_f, bih_b, bhh_b, GX);
  gru_scan_kernel<<<dim3(128), 1024, 0, stream>>>(Whh_f, Whh_b, bhh_f, bhh_b, D, GX, out);
}

// Round 4
// 3187.943 us; speedup vs baseline: 1.7386x; 1.2375x over previous
//
#include <hip/hip_runtime.h>
#include <cstdint>
#include <cstddef>

// DiscontinuedGRU: SEQ=2048, B=64, I=256, H=256.
// Pipeline:
//   K0a: X fp32 -> bf16 (ws)
//   K0b: Wih_f|Wih_b fp32 -> bf16 concat (ws)
//   K1 : GX[131072][1536] f16 = Xb @ Wcat^T + (bih + bhh_{r,z} folded; bhh_n NOT folded)
//   K2 : 128 WGs (one per (dir,batch) chain), Whh f16 register-resident,
//        v_dot2 matvec per step + gate math; h state in LDS (f16).
//   R3: kq-quad reduce via DPP quad_perm (VALU) instead of ds_swizzle (−117us, kept).
//   R4: (a) GX/D loads issued at TOP of step into raw regs, consumed after the mid
//        __syncthreads — the barrier's vmcnt(0) drain is free since the loads have the
//        whole ~2000cy matvec phase to land. Crosses no barrier backwards, so no asm
//        barrier needed. (b) gh2 second half-copy at offset 776 (was 768): 768%32==0
//        made the 16-lane partial-wave ds_write_b32 pair 2 lanes/bank (5.03e7 conflict
//        cycles = 192/step/WG); +8 offset de-conflicts.
//   PERMANENT REVERTS (measured poison): lgkm-only asm barrier (+~1500us, R1/R2);
//        prefetch-across-bottom-barrier (requires said barrier).
// ws layout: Xb 67,108,864 B | Wcat 786,432 B | GX 402,653,184 B  (total ~449 MB)

#define SEQ 2048
#define BATCH 64

typedef __attribute__((ext_vector_type(8))) short short8;
typedef __attribute__((ext_vector_type(4))) float floatx4;
typedef __attribute__((ext_vector_type(2))) _Float16 h2;

#if defined(__has_builtin)
#if __has_builtin(__builtin_amdgcn_fdot2)
#define HAS_FDOT2 1
#endif
#if __has_builtin(__builtin_amdgcn_update_dpp)
#define HAS_DPP 1
#endif
#endif

__device__ inline float fdot2f(h2 a, h2 b, float c){
#ifdef HAS_FDOT2
  return __builtin_amdgcn_fdot2(a, b, c, false);
#else
  return c + (float)a.x * (float)b.x + (float)a.y * (float)b.y;
#endif
}

// sum over the 4 lanes of each quad (lane bits 0,1) — VALU DPP, no DS-pipe traffic.
__device__ inline float quad_add(float x){
#ifdef HAS_DPP
  int t1 = __builtin_amdgcn_update_dpp(0, __builtin_bit_cast(int, x), 0xB1, 0xF, 0xF, false); // quad_perm [1,0,3,2]
  x += __builtin_bit_cast(float, t1);
  int t2 = __builtin_amdgcn_update_dpp(0, __builtin_bit_cast(int, x), 0x4E, 0xF, 0xF, false); // quad_perm [2,3,0,1]
  x += __builtin_bit_cast(float, t2);
  return x;
#else
  x += __shfl_xor(x, 1);
  x += __shfl_xor(x, 2);
  return x;
#endif
}

__device__ inline unsigned short f2bf(float f){
  union { float f; unsigned int u; } a; a.f = f;
  unsigned int u = a.u;
  unsigned int r = (u + 0x7fffu + ((u >> 16) & 1u)) >> 16;
  return (unsigned short)r;
}

__global__ __launch_bounds__(256) void cvt_x_kernel(const float* __restrict__ X,
                                                    unsigned short* __restrict__ Xb){
  size_t i = (size_t)blockIdx.x * 256 + threadIdx.x;   // one float4 per thread
  float4 v = ((const float4*)X)[i];
  ushort4 o;
  o.x = f2bf(v.x); o.y = f2bf(v.y); o.z = f2bf(v.z); o.w = f2bf(v.w);
  ((ushort4*)Xb)[i] = o;
}

__global__ __launch_bounds__(256) void cvt_w_kernel(const float* __restrict__ Wf,
                                                    const float* __restrict__ Wb,
                                                    unsigned short* __restrict__ Wcat){
  int i = blockIdx.x * 256 + threadIdx.x;              // 0..393215
  float v = (i < 768 * 256) ? Wf[i] : Wb[i - 768 * 256];
  Wcat[i] = f2bf(v);
}

// ---------------- GX GEMM: M=131072, N=1536, K=256, bf16 MFMA ----------------
// Block: 256 thr (4 waves). Tile BM=64, BN=128, BK=64. Wave w: rows [16w,16w+16) x 128 cols.
__global__ __launch_bounds__(256) void gx_gemm_kernel(
    const unsigned short* __restrict__ Xb,    // [131072][256] bf16
    const unsigned short* __restrict__ Wcat,  // [1536][256]  bf16 (row n, k-contig = B^T)
    const float* __restrict__ bih_f, const float* __restrict__ bhh_f,
    const float* __restrict__ bih_b, const float* __restrict__ bhh_b,
    _Float16* __restrict__ GX)                // [131072][1536] f16
{
  __shared__ unsigned short Al[64][72];   // +8 pad: stride 36 words
  __shared__ unsigned short Bl[128][72];
  const int tid  = threadIdx.x;
  const int lane = tid & 63;
  const int w    = tid >> 6;
  const size_t m0 = (size_t)blockIdx.x * 64;
  const int    n0 = blockIdx.y * 128;

  floatx4 acc[8];
  #pragma unroll
  for (int i = 0; i < 8; i++) acc[i] = (floatx4)0.f;

  const int ar = tid >> 2, ak = (tid & 3) * 16;   // A stage: 16 halves/thread
  const int bn = tid >> 1, bk = (tid & 1) * 32;   // B stage: 32 halves/thread

  for (int kc = 0; kc < 4; kc++){
    const int kb = kc * 64;
    { const uint4* s = (const uint4*)(Xb + (m0 + ar) * 256 + kb + ak);
      uint4 u0 = s[0], u1 = s[1];
      *(uint4*)&Al[ar][ak]     = u0;
      *(uint4*)&Al[ar][ak + 8] = u1;
    }
    { const uint4* s = (const uint4*)(Wcat + (size_t)(n0 + bn) * 256 + kb + bk);
      uint4 u0 = s[0], u1 = s[1], u2 = s[2], u3 = s[3];
      *(uint4*)&Bl[bn][bk]      = u0;
      *(uint4*)&Bl[bn][bk + 8]  = u1;
      *(uint4*)&Bl[bn][bk + 16] = u2;
      *(uint4*)&Bl[bn][bk + 24] = u3;
    }
    __syncthreads();
    #pragma unroll
    for (int ks = 0; ks < 2; ks++){
      const int kl = ks * 32 + (lane >> 4) * 8;
      short8 af = *(const short8*)&Al[w * 16 + (lane & 15)][kl];
      #pragma unroll
      for (int nt = 0; nt < 8; nt++){
        short8 bf = *(const short8*)&Bl[nt * 16 + (lane & 15)][kl];
        acc[nt] = __builtin_amdgcn_mfma_f32_16x16x32_bf16(af, bf, acc[nt], 0, 0, 0);
      }
    }
    __syncthreads();
  }
  // epilogue: D col = lane&15, row = (lane>>4)*4 + reg  [verified m89/m91]
  #pragma unroll
  for (int nt = 0; nt < 8; nt++){
    const int n_g = n0 + nt * 16 + (lane & 15);
    const int nl  = (n_g < 768) ? n_g : n_g - 768;
    const float* bih = (n_g < 768) ? bih_f : bih_b;
    const float* bhh = (n_g < 768) ? bhh_f : bhh_b;
    // fold bih (all gates) + bhh for r,z only; bhh_n applied inside scan (r * (hn + bhh_n))
    const float bias = bih[nl] + ((nl < 512) ? bhh[nl] : 0.f);
    #pragma unroll
    for (int r = 0; r < 4; r++){
      const size_t m_g = m0 + w * 16 + (lane >> 4) * 4 + r;
      GX[m_g * 1536 + n_g] = (_Float16)(acc[nt][r] + bias);
    }
  }
}

// ---------------- Recurrent scan: 128 WGs x 1024 thr, 1 chain each ----------------
// thread t: j0 = t>>3 (0..127), kq = t&7 (k-slice of 32). Owns 6 gh rows: j0 + 128q.
// Whh f16 in 96 VGPRs/thread. h state: LDS f16, slice-padded (stride 40 halves) so the
// 8 distinct per-wave b128 addresses land on 8 distinct bank quads (conflict-free).
#define GH_STRIDE 776   // was 768; 768%32==0 paired half-copies onto the same bank
__global__ __launch_bounds__(1024) void gru_scan_kernel(
    const float* __restrict__ Whh_f, const float* __restrict__ Whh_b,
    const float* __restrict__ bhh_f, const float* __restrict__ bhh_b,
    const int* __restrict__ D,
    const _Float16* __restrict__ GX,
    float* __restrict__ out)
{
  const int wg  = blockIdx.x;       // 0..127
  const int dir = wg & 1;
  const int b   = wg >> 1;
  const float* Whh = dir ? Whh_b : Whh_f;
  const float* bhh = dir ? bhh_b : bhh_f;
  const int tid   = threadIdx.x;
  const int j0    = tid >> 3;
  const int kq    = tid & 7;
  const int kbase = kq * 32;

  __shared__ _Float16 hbuf[8 * 40];        // slice q at q*40 (32 valid + 8 pad)
  __shared__ float    gh2[2 * GH_STRIDE];  // two partial copies (kq groups 0-3 / 4-7)

  // persistent weights: rows j0 + 128q, k in [kbase, kbase+32)
  h2 wreg[6][4][4];
  #pragma unroll
  for (int q = 0; q < 6; q++){
    const float* wr = Whh + (size_t)(j0 + 128 * q) * 256 + kbase;
    #pragma unroll
    for (int c = 0; c < 4; c++){
      float4 f0 = *(const float4*)(wr + c * 8);
      float4 f1 = *(const float4*)(wr + c * 8 + 4);
      wreg[q][c][0] = h2{(_Float16)f0.x, (_Float16)f0.y};
      wreg[q][c][1] = h2{(_Float16)f0.z, (_Float16)f0.w};
      wreg[q][c][2] = h2{(_Float16)f1.x, (_Float16)f1.y};
      wreg[q][c][3] = h2{(_Float16)f1.z, (_Float16)f1.w};
    }
  }

  const bool gate = (tid < 256);      // waves 0-3, whole waves -> no divergence cost elsewhere
  float h_reg = 0.f;                  // fp32 h_in[j] for gate thread j = tid
  float bhhn  = 0.f;
  if (gate){
    bhhn = bhh[512 + tid];
    hbuf[((tid >> 5) * 40) + (tid & 31)] = (_Float16)0.f;
  }
  __syncthreads();

  for (int step = 0; step < SEQ; step++){
    const int t = dir ? (SEQ - 1 - step) : step;

    // Issue this step's GX + D loads NOW, into RAW registers (no convert — a convert
    // here would force the waitcnt at the issue point). They land during the matvec
    // phase; the mid __syncthreads' vmcnt(0) drain is then free.
    _Float16 pgr = (_Float16)0.f, pgz = (_Float16)0.f, pgn = (_Float16)0.f;
    int mraw = 0;
    if (gate){
      const _Float16* gx = GX + ((size_t)t * BATCH + b) * 1536 + dir * 768;
      pgr = gx[tid];
      pgz = gx[256 + tid];
      pgn = gx[512 + tid];
      // fwd uses D[t+1] (clamped at last step, value dead); bwd uses D[t]
      const int tm = dir ? t : ((step < SEQ - 1) ? (t + 1) : t);
      mraw = D[(size_t)tm * BATCH + b];
    }

    float acc[6] = {0.f, 0.f, 0.f, 0.f, 0.f, 0.f};
    #pragma unroll
    for (int c = 0; c < 4; c++){
      uint4 u = *(const uint4*)&hbuf[kq * 40 + c * 8];
      h2 p0 = __builtin_bit_cast(h2, u.x);
      h2 p1 = __builtin_bit_cast(h2, u.y);
      h2 p2 = __builtin_bit_cast(h2, u.z);
      h2 p3 = __builtin_bit_cast(h2, u.w);
      #pragma unroll
      for (int q = 0; q < 6; q++){
        acc[q] = fdot2f(wreg[q][c][0], p0, acc[q]);
        acc[q] = fdot2f(wreg[q][c][1], p1, acc[q]);
        acc[q] = fdot2f(wreg[q][c][2], p2, acc[q]);
        acc[q] = fdot2f(wreg[q][c][3], p3, acc[q]);
      }
    }
    // reduce kq pairs/quads on the VALU pipe (DPP quad_perm)
    #pragma unroll
    for (int q = 0; q < 6; q++) acc[q] = quad_add(acc[q]);
    if ((tid & 3) == 0){               // kq in {0,4}
      float* g = gh2 + ((tid >> 2) & 1) * GH_STRIDE;
      #pragma unroll
      for (int q = 0; q < 6; q++) g[j0 + 128 * q] = acc[q];
    }
    __syncthreads();

    if (gate){
      const int j = tid;
      // consume the loads issued before the matvec (resident by now)
      const float gxr = (float)pgr;
      const float gxz = (float)pgz;
      const float gxn = (float)pgn;
      float mnext = (float)mraw;
      if (dir == 0 && step == SEQ - 1) mnext = 0.f;   // clamped tail value is dead
      const float ghr = gh2[j]       + gh2[GH_STRIDE + j];
      const float ghz = gh2[256 + j] + gh2[GH_STRIDE + 256 + j];
      const float ghn = gh2[512 + j] + gh2[GH_STRIDE + 512 + j];
      const float r = 1.f / (1.f + __expf(-(gxr + ghr)));
      const float z = 1.f / (1.f + __expf(-(gxz + ghz)));
      const float e = __expf(2.f * (gxn + r * (ghn + bhhn)));
      const float n = 1.f - 2.f / (e + 1.f);
      const float hnew = (1.f - z) * n + z * h_reg;
      const size_t row = (size_t)t * BATCH + b;
      out[row * 512 + dir * 256 + j] = hnew;
      h_reg = (1.f - mnext) * hnew;
      hbuf[((j >> 5) * 40) + (j & 31)] = (_Float16)h_reg;
    }
    __syncthreads();
  }
}

extern "C" void kernel_launch(void* const* d_in, const int* in_sizes, int n_in,
                              void* d_out, int out_size, void* d_ws, size_t ws_size,
                              hipStream_t stream)
{
  const float* X     = (const float*)d_in[0];
  const int*   D     = (const int*)  d_in[1];
  const float* Wih_f = (const float*)d_in[2];
  const float* Whh_f = (const float*)d_in[3];
  const float* bih_f = (const float*)d_in[4];
  const float* bhh_f = (const float*)d_in[5];
  const float* Wih_b = (const float*)d_in[6];
  const float* Whh_b = (const float*)d_in[7];
  const float* bih_b = (const float*)d_in[8];
  const float* bhh_b = (const float*)d_in[9];
  float* out = (float*)d_out;

  char* ws = (char*)d_ws;
  unsigned short* Xb   = (unsigned short*)ws;               // 67,108,864 B
  unsigned short* Wcat = (unsigned short*)(ws + 67108864);  //    786,432 B
  _Float16*       GX   = (_Float16*)(ws + 67895296);        // 402,653,184 B

  cvt_x_kernel<<<dim3(32768), 256, 0, stream>>>(X, Xb);
  cvt_w_kernel<<<dim3(1536), 256, 0, stream>>>(Wih_f, Wih_b, Wcat);
  gx_gemm_kernel<<<dim3(2048, 12), 256, 0, stream>>>(Xb, Wcat, bih_f, bhh_f, bih_b, bhh_b, GX);
  gru_scan_kernel<<<dim3(128), 1024, 0, stream>>>(Whh_f, Whh_b, bhh_f, bhh_b, D, GX, out);
}